// Round 1
// baseline (2273.252 us; speedup 1.0000x reference)
//
#include <hip/hip_runtime.h>
#include <hip/hip_bf16.h>

// Problem: N=2048, F_IN=128, F_OUT=64
// out[j,f] = sum_{i,k} A[j,i] H[i,f] mh[i,k] H[k,f] mf[j,k],  H = X@W + b
// R3: fi=4 f-values per block (doubles MFMA per LDS byte vs fi=2; the R2
// profile showed wall = MFMA-cycles + LDS-cycles additive, so halving
// LDS traffic per MFMA attacks the non-overlapped half). acc[4][4][4]
// (256 AGPR) -> 1 wave/SIMD, grid 256 = 1 block/CU. Per-ktile partials
// accumulate in LDS `red` (frees outp's 64 VGPRs to stay under spill).

typedef __attribute__((ext_vector_type(8))) _Float16 f16x8;
typedef __attribute__((ext_vector_type(4))) _Float16 f16x4;
typedef __attribute__((ext_vector_type(4))) float f32x4;

#define N 2048
#define FOUT 64
#define FIN 128
#define BI 64          // i-tile per stage
#define NIT 512        // 16 ktiles * 32 i-steps

__device__ __forceinline__ void gl_lds16(const _Float16* g, _Float16* l) {
    __builtin_amdgcn_global_load_lds(
        (const __attribute__((address_space(1))) void*)g,
        (__attribute__((address_space(3))) void*)l, 16, 0, 0);
}

// ---------------- prep kernels ----------------

__global__ __launch_bounds__(256) void k_h(const float* __restrict__ X,
                                           const float* __restrict__ W,
                                           const float* __restrict__ bias,
                                           float* __restrict__ HT,
                                           _Float16* __restrict__ HTh) {
    __shared__ float Ws[FIN * FOUT];
    __shared__ float Xs[4 * FIN];
    int t = threadIdx.x;
#pragma unroll
    for (int s = 0; s < 32; ++s) Ws[t + 256 * s] = W[t + 256 * s];
    int i0 = blockIdx.x * 4;
#pragma unroll
    for (int s = 0; s < 2; ++s) { int idx = t + 256 * s; Xs[idx] = X[(size_t)i0 * FIN + idx]; }
    __syncthreads();
    int f = t & 63, il = t >> 6;
    float h = bias[f];
#pragma unroll
    for (int p = 0; p < FIN; ++p) h = fmaf(Xs[il * FIN + p], Ws[p * FOUT + f], h);
    int i = i0 + il;
    HT[f * N + i] = h;
    HTh[f * N + i] = (_Float16)h;
}

__global__ __launch_bounds__(256) void k_a2h(const float* __restrict__ A,
                                             _Float16* __restrict__ Ah) {
    int g = blockIdx.x * 256 + threadIdx.x;
    float4 v = ((const float4*)A)[g];
    f16x4 o;
    o[0] = (_Float16)v.x; o[1] = (_Float16)v.y; o[2] = (_Float16)v.z; o[3] = (_Float16)v.w;
    ((f16x4*)Ah)[g] = o;
}

__global__ __launch_bounds__(256) void k_mht(const float* __restrict__ mh,
                                             _Float16* __restrict__ mhT) {
    __shared__ float tile[64][65];
    int t = threadIdx.x;
    int bx = blockIdx.x & 31;
    int by = blockIdx.x >> 5;
#pragma unroll
    for (int s = 0; s < 16; ++s) {
        int lin = t + 256 * s;
        int r = lin >> 6, c = lin & 63;
        tile[r][c] = mh[(size_t)(by * 64 + r) * N + bx * 64 + c];
    }
    __syncthreads();
#pragma unroll
    for (int s = 0; s < 16; ++s) {
        int lin = t + 256 * s;
        int kr = lin >> 6, ic = lin & 63;
        mhT[(size_t)(bx * 64 + kr) * N + by * 64 + ic] = (_Float16)tile[ic][kr];
    }
}

// ---------------- main kernel ----------------
// grid 256 = 16 jtiles (bid>>4) * 16 fgroups (bid&15); block = 128j x 128k x 4f.
// Wave w: wj=(w&1)*64, wk=(w>>1)*64; per-wave 64x64 per f.
// LDS tile row = 64 halves = 8 chunks of 16B; phys_chunk = log_chunk ^ (row&7).
__global__ __launch_bounds__(256, 1) void k_main(const float* __restrict__ mf,
                                                 const float* __restrict__ HT,
                                                 const _Float16* __restrict__ HTh,
                                                 const _Float16* __restrict__ Ah,
                                                 const _Float16* __restrict__ mhT,
                                                 float* __restrict__ out) {
    __shared__ _Float16 tiles[2][2][128 * BI];  // [buf][a=0/b=1][row*64+..] 64KB
    __shared__ _Float16 hbuf[4][N];             // H fp16 rows for f0..f0+3: 16KB
    __shared__ float red[4][4][64];             // [fi][w][j-slot] 4KB

    int t = threadIdx.x;
    int jbase = (blockIdx.x >> 4) << 7;
    int f0 = (blockIdx.x & 15) << 2;
    int w = t >> 6, lane = t & 63, q = lane >> 4, l16 = lane & 15;
    int wj = (w & 1) << 6, wk = (w >> 1) << 6;

    // --- stage H rows (once) ---
#pragma unroll
    for (int s = 0; s < 4; ++s) {
        int idx = t + 256 * s;                 // 0..1023 ; fi=idx>>8, chunk=idx&255
        ((f16x8*)hbuf)[idx] = *(const f16x8*)&HTh[(size_t)(f0 + (idx >> 8)) * N + (idx & 255) * 8];
    }
    // --- zero red (ordered vs first epilogue by loop barriers) ---
    ((float*)red)[t]       = 0.f;
    ((float*)red)[t + 256] = 0.f;
    ((float*)red)[t + 512] = 0.f;
    ((float*)red)[t + 768] = 0.f;

    // --- staging voffsets (global_load_lds: lane l -> ldsbase + l*16) ---
    int lrow = lane >> 3;                      // row within 8-row call
    int lchunk = (lane & 7) ^ lrow;            // logical chunk (XOR swizzle)
    int a_base = (jbase + w * 32 + lrow) * N + lchunk * 8;
    int b_base = (w * 32 + lrow) * N + lchunk * 8;   // + kbase*N per ktile
    int lds_w = w * 2048;                      // (w*32 rows)*64 halves

    // --- prefetch iteration 0 ---
    {
        const _Float16* pa = Ah + a_base;
        const _Float16* pb = mhT + b_base;
        _Float16* la = &tiles[0][0][lds_w];
        _Float16* lb = &tiles[0][1][lds_w];
#pragma unroll
        for (int c = 0; c < 4; ++c) {
            gl_lds16(pa + c * 8 * N, la + c * 512);
            gl_lds16(pb + c * 8 * N, lb + c * 512);
        }
    }

    f32x4 acc[4][4][4];
#pragma unroll
    for (int fi = 0; fi < 4; ++fi)
#pragma unroll
        for (int a = 0; a < 4; ++a)
#pragma unroll
            for (int b = 0; b < 4; ++b) acc[fi][a][b] = (f32x4){0.f, 0.f, 0.f, 0.f};

    for (int it = 0; it < NIT; ++it) {
        int buf = it & 1;
        int ibase = (it & 31) << 6;
        int kbase = (it >> 5) << 7;

        __syncthreads();   // drains prefetch(it) [vmcnt0] + frees other buffer

        // --- prefetch it+1 into other buffer (overlaps compute below) ---
        if (it + 1 < NIT) {
            int ib2 = ((it + 1) & 31) << 6;
            int kt2 = (it + 1) >> 5;
            const _Float16* pa = Ah + a_base + ib2;
            const _Float16* pb = mhT + b_base + kt2 * 128 * N + ib2;
            _Float16* la = &tiles[buf ^ 1][0][lds_w];
            _Float16* lb = &tiles[buf ^ 1][1][lds_w];
#pragma unroll
            for (int c = 0; c < 4; ++c) {
                gl_lds16(pa + c * 8 * N, la + c * 512);
                gl_lds16(pb + c * 8 * N, lb + c * 512);
            }
        }

        // --- compute from tiles[buf] ---
        const _Float16* ta = tiles[buf][0];
        const _Float16* tb = tiles[buf][1];
#pragma unroll
        for (int s = 0; s < 2; ++s) {
            f16x8 ar[4], br[4], h[4];
#pragma unroll
            for (int x = 0; x < 4; ++x) {
                int row = wj + x * 16 + l16;
                ar[x] = *(const f16x8*)&ta[row * 64 + (((q + 4 * s) ^ (l16 & 7)) * 8)];
            }
#pragma unroll
            for (int x = 0; x < 4; ++x) {
                int row = wk + x * 16 + l16;
                br[x] = *(const f16x8*)&tb[row * 64 + (((q + 4 * s) ^ (l16 & 7)) * 8)];
            }
#pragma unroll
            for (int fi = 0; fi < 4; ++fi)
                h[fi] = *(const f16x8*)&hbuf[fi][ibase + s * 32 + q * 8];
#pragma unroll
            for (int fi = 0; fi < 4; ++fi)
#pragma unroll
                for (int jj = 0; jj < 4; ++jj) {
                    f16x8 a = ar[jj] * h[fi];
#pragma unroll
                    for (int kk = 0; kk < 4; ++kk)
                        acc[fi][jj][kk] = __builtin_amdgcn_mfma_f32_16x16x32_f16(
                            a, br[kk], acc[fi][jj][kk], 0, 0, 0);
                }
        }

        // --- per-ktile epilogue: fold k into red (LDS) partials ---
        if ((it & 31) == 31) {
            float hk[4][4];   // [fi][kk]
#pragma unroll
            for (int kk = 0; kk < 4; ++kk) {
                int kg = kbase + wk + kk * 16 + l16;
#pragma unroll
                for (int fi = 0; fi < 4; ++fi) hk[fi][kk] = HT[(size_t)(f0 + fi) * N + kg];
            }
#pragma unroll
            for (int jj = 0; jj < 4; ++jj) {
                float tt[4][4];   // [fi][r]
#pragma unroll
                for (int fi = 0; fi < 4; ++fi)
#pragma unroll
                    for (int r = 0; r < 4; ++r) tt[fi][r] = 0.f;
                int jrow = jbase + wj + jj * 16 + q * 4;
#pragma unroll
                for (int kk = 0; kk < 4; ++kk) {
                    int kg = kbase + wk + kk * 16 + l16;
#pragma unroll
                    for (int r = 0; r < 4; ++r) {
                        float m = mf[(size_t)(jrow + r) * N + kg];
#pragma unroll
                        for (int fi = 0; fi < 4; ++fi)
                            tt[fi][r] = fmaf(acc[fi][jj][kk][r], m * hk[fi][kk], tt[fi][r]);
                    }
                }
#pragma unroll
                for (int fi = 0; fi < 4; ++fi)
#pragma unroll
                    for (int r = 0; r < 4; ++r) {
                        float v = tt[fi][r];
                        v += __shfl_xor(v, 1);
                        v += __shfl_xor(v, 2);
                        v += __shfl_xor(v, 4);
                        v += __shfl_xor(v, 8);
                        // single writer per slot: (fi, w, jj*16+q*4+r)
                        if (l16 == 0) red[fi][w][jj * 16 + q * 4 + r] += v;
                    }
            }
#pragma unroll
            for (int fi = 0; fi < 4; ++fi)
#pragma unroll
                for (int a = 0; a < 4; ++a)
#pragma unroll
                    for (int b = 0; b < 4; ++b) acc[fi][a][b] = (f32x4){0.f, 0.f, 0.f, 0.f};
        }
    }

    // --- cross-wave reduce + store ---
    __syncthreads();
    if (t < 128) {
        int j = t;
#pragma unroll
        for (int fi = 0; fi < 4; ++fi) {
            float v = (j < 64) ? (red[fi][0][j] + red[fi][2][j])
                               : (red[fi][1][j - 64] + red[fi][3][j - 64]);
            out[(size_t)(jbase + j) * FOUT + f0 + fi] = v;
        }
    }
}

// ---------------- launch ----------------
extern "C" void kernel_launch(void* const* d_in, const int* in_sizes, int n_in,
                              void* d_out, int out_size, void* d_ws, size_t ws_size,
                              hipStream_t stream) {
    const float* X    = (const float*)d_in[0];
    const float* A    = (const float*)d_in[1];
    const float* mf   = (const float*)d_in[2];
    const float* mh   = (const float*)d_in[3];
    const float* W    = (const float*)d_in[4];
    const float* bias = (const float*)d_in[5];
    float* out = (float*)d_out;

    float*    HT  = (float*)d_ws;
    _Float16* HTh = (_Float16*)((char*)d_ws + 524288);
    _Float16* Ah  = (_Float16*)((char*)d_ws + 1048576);
    _Float16* mhT = (_Float16*)((char*)d_ws + 1048576 + 8388608);

    k_h<<<N / 4, 256, 0, stream>>>(X, W, bias, HT, HTh);
    k_a2h<<<(N * N / 4) / 256, 256, 0, stream>>>(A, Ah);
    k_mht<<<(N / 64) * (N / 64), 256, 0, stream>>>(mh, mhT);
    k_main<<<16 * 16, 256, 0, stream>>>(mf, HT, HTh, Ah, mhT, out);
}

// Round 2
// 1449.959 us; speedup vs baseline: 1.5678x; 1.5678x over previous
//
#include <hip/hip_runtime.h>
#include <hip/hip_bf16.h>

// Problem: N=2048, F_IN=128, F_OUT=64
// out[j,f] = sum_{i,k} A[j,i] H[i,f] mh[i,k] H[k,f] mf[j,k],  H = X@W + b
// R4: fi=2 (R2 math, verified) + triple-buffered LDS with COUNTED vmcnt(8)
// (stage stays in flight across barriers) + register-pipelined fragments:
// ds_read frags(t+1) issued before MFMA(t), consumed next iter -> LDS port
// runs under the MFMA phase instead of alternating with it. 1 wave/SIMD
// (launch_bounds(256,1)): frag double-set (128 VGPR) + acc (128 AGPR).
// R3 lesson: acc[4][..] (256 regs) spills -- keep acc at 128.

typedef __attribute__((ext_vector_type(8))) _Float16 f16x8;
typedef __attribute__((ext_vector_type(4))) _Float16 f16x4;
typedef __attribute__((ext_vector_type(4))) float f32x4;

#define N 2048
#define FOUT 64
#define FIN 128
#define NIT 512        // 16 ktiles * 32 i-steps

__device__ __forceinline__ void gl_lds16(const _Float16* g, _Float16* l) {
    __builtin_amdgcn_global_load_lds(
        (const __attribute__((address_space(1))) void*)g,
        (__attribute__((address_space(3))) void*)l, 16, 0, 0);
}

// ---------------- prep kernels ----------------

__global__ __launch_bounds__(256) void k_h(const float* __restrict__ X,
                                           const float* __restrict__ W,
                                           const float* __restrict__ bias,
                                           float* __restrict__ HT,
                                           _Float16* __restrict__ HTh) {
    __shared__ float Ws[FIN * FOUT];
    __shared__ float Xs[4 * FIN];
    int t = threadIdx.x;
#pragma unroll
    for (int s = 0; s < 32; ++s) Ws[t + 256 * s] = W[t + 256 * s];
    int i0 = blockIdx.x * 4;
#pragma unroll
    for (int s = 0; s < 2; ++s) { int idx = t + 256 * s; Xs[idx] = X[(size_t)i0 * FIN + idx]; }
    __syncthreads();
    int f = t & 63, il = t >> 6;
    float h = bias[f];
#pragma unroll
    for (int p = 0; p < FIN; ++p) h = fmaf(Xs[il * FIN + p], Ws[p * FOUT + f], h);
    int i = i0 + il;
    HT[f * N + i] = h;
    HTh[f * N + i] = (_Float16)h;
}

__global__ __launch_bounds__(256) void k_a2h(const float* __restrict__ A,
                                             _Float16* __restrict__ Ah) {
    int g = blockIdx.x * 256 + threadIdx.x;
    float4 v = ((const float4*)A)[g];
    f16x4 o;
    o[0] = (_Float16)v.x; o[1] = (_Float16)v.y; o[2] = (_Float16)v.z; o[3] = (_Float16)v.w;
    ((f16x4*)Ah)[g] = o;
}

__global__ __launch_bounds__(256) void k_mht(const float* __restrict__ mh,
                                             _Float16* __restrict__ mhT) {
    __shared__ float tile[64][65];
    int t = threadIdx.x;
    int bx = blockIdx.x & 31;
    int by = blockIdx.x >> 5;
#pragma unroll
    for (int s = 0; s < 16; ++s) {
        int lin = t + 256 * s;
        int r = lin >> 6, c = lin & 63;
        tile[r][c] = mh[(size_t)(by * 64 + r) * N + bx * 64 + c];
    }
    __syncthreads();
#pragma unroll
    for (int s = 0; s < 16; ++s) {
        int lin = t + 256 * s;
        int kr = lin >> 6, ic = lin & 63;
        mhT[(size_t)(bx * 64 + kr) * N + by * 64 + ic] = (_Float16)tile[ic][kr];
    }
}

// ---------------- main kernel ----------------
// grid 512 = 16 jtiles (bid>>5) * 32 fgroups (bid&31); block = 128j x 128k x 2f.
// Wave w: wj=(w&1)*64, wk=(w>>1)*64; per-wave 64x64 per f.
// LDS tile row = 64 halves = 8 chunks of 16B; phys_chunk = log_chunk ^ (row&7).

#define WAITV8 { asm volatile("s_waitcnt vmcnt(8)" ::: "memory"); __builtin_amdgcn_sched_barrier(0); }
#define WAITV0 { asm volatile("s_waitcnt vmcnt(0)" ::: "memory"); __builtin_amdgcn_sched_barrier(0); }
#define LGKM0  { asm volatile("s_waitcnt lgkmcnt(0)" ::: "memory"); __builtin_amdgcn_sched_barrier(0); }
#define BAR    { __builtin_amdgcn_s_barrier(); __builtin_amdgcn_sched_barrier(0); }

// stage tile for iteration X into LDS buffer X%3 (8 gl_lds per wave)
#define STAGE_STEP(X)                                                         \
  {                                                                           \
    int bs_ = (X) % 3;                                                        \
    int ib_ = ((X) & 31) << 6;                                                \
    int kt_ = (X) >> 5;                                                       \
    const _Float16* pa_ = Ah + a_base + ib_;                                  \
    const _Float16* pb_ = mhT + b_base + (size_t)kt_ * 128 * N + ib_;         \
    _Float16* la_ = &tiles[bs_][0][lds_w];                                    \
    _Float16* lb_ = &tiles[bs_][1][lds_w];                                    \
    _Pragma("unroll")                                                         \
    for (int c_ = 0; c_ < 4; ++c_) {                                          \
      gl_lds16(pa_ + c_ * 8 * N, la_ + c_ * 512);                             \
      gl_lds16(pb_ + c_ * 8 * N, lb_ + c_ * 512);                             \
    }                                                                         \
  }

// read fragments + h rows for an iteration from LDS buffer TB into reg set
#define READ_STEP(AR, BR, HH, TB, IB)                                         \
  {                                                                           \
    const _Float16* ta_ = &tiles[TB][0][0];                                   \
    const _Float16* tb_ = &tiles[TB][1][0];                                   \
    _Pragma("unroll")                                                         \
    for (int s_ = 0; s_ < 2; ++s_) {                                          \
      HH[s_][0] = *(const f16x8*)&hbuf[0][(IB) + s_ * 32 + q * 8];            \
      HH[s_][1] = *(const f16x8*)&hbuf[1][(IB) + s_ * 32 + q * 8];            \
      _Pragma("unroll")                                                       \
      for (int x_ = 0; x_ < 4; ++x_) {                                        \
        AR[s_][x_] = *(const f16x8*)&ta_[(wj + x_ * 16 + l16) * 64 +          \
                                         (((q + 4 * s_) ^ (l16 & 7)) * 8)];   \
        BR[s_][x_] = *(const f16x8*)&tb_[(wk + x_ * 16 + l16) * 64 +          \
                                         (((q + 4 * s_) ^ (l16 & 7)) * 8)];   \
      }                                                                       \
    }                                                                         \
  }

#define EPILOGUE(T)                                                           \
  {                                                                           \
    int kbase_ = ((T) >> 5) << 7;                                             \
    _Pragma("unroll")                                                         \
    for (int jj = 0; jj < 4; ++jj) {                                          \
      float t0[4] = {0.f, 0.f, 0.f, 0.f};                                     \
      float t1[4] = {0.f, 0.f, 0.f, 0.f};                                     \
      int jrow = jbase + wj + jj * 16 + q * 4;                                \
      _Pragma("unroll")                                                       \
      for (int kk = 0; kk < 4; ++kk) {                                        \
        int kg = kbase_ + wk + kk * 16 + l16;                                 \
        float hk0 = HT[f0 * N + kg];                                          \
        float hk1 = HT[(f0 + 1) * N + kg];                                    \
        _Pragma("unroll")                                                     \
        for (int r = 0; r < 4; ++r) {                                         \
          float m = mf[(size_t)(jrow + r) * N + kg];                          \
          t0[r] = fmaf(acc[0][jj][kk][r], m * hk0, t0[r]);                    \
          t1[r] = fmaf(acc[1][jj][kk][r], m * hk1, t1[r]);                    \
        }                                                                     \
      }                                                                       \
      _Pragma("unroll")                                                       \
      for (int r = 0; r < 4; ++r) {                                           \
        float v0 = t0[r], v1 = t1[r];                                         \
        v0 += __shfl_xor(v0, 1); v1 += __shfl_xor(v1, 1);                     \
        v0 += __shfl_xor(v0, 2); v1 += __shfl_xor(v1, 2);                     \
        v0 += __shfl_xor(v0, 4); v1 += __shfl_xor(v1, 4);                     \
        v0 += __shfl_xor(v0, 8); v1 += __shfl_xor(v1, 8);                     \
        if (l16 == 0) {                                                       \
          red[0][w][jj * 16 + q * 4 + r] += v0;                               \
          red[1][w][jj * 16 + q * 4 + r] += v1;                               \
        }                                                                     \
      }                                                                       \
    }                                                                         \
    _Pragma("unroll")                                                         \
    for (int a_ = 0; a_ < 4; ++a_)                                            \
      _Pragma("unroll")                                                       \
      for (int b_ = 0; b_ < 4; ++b_) {                                        \
        acc[0][a_][b_] = (f32x4){0.f, 0.f, 0.f, 0.f};                         \
        acc[1][a_][b_] = (f32x4){0.f, 0.f, 0.f, 0.f};                         \
      }                                                                       \
  }

// MFMA phase: purely register-resident (frags+h prefetched, acc in AGPR)
#define COMPUTE_STEP(AR, BR, HH, T)                                           \
  {                                                                           \
    _Pragma("unroll")                                                         \
    for (int s_ = 0; s_ < 2; ++s_) {                                          \
      _Pragma("unroll")                                                       \
      for (int jj = 0; jj < 4; ++jj) {                                        \
        f16x8 a0_ = AR[s_][jj] * HH[s_][0];                                   \
        f16x8 a1_ = AR[s_][jj] * HH[s_][1];                                   \
        _Pragma("unroll")                                                     \
        for (int kk = 0; kk < 4; ++kk) {                                      \
          acc[0][jj][kk] = __builtin_amdgcn_mfma_f32_16x16x32_f16(            \
              a0_, BR[s_][kk], acc[0][jj][kk], 0, 0, 0);                      \
          acc[1][jj][kk] = __builtin_amdgcn_mfma_f32_16x16x32_f16(            \
              a1_, BR[s_][kk], acc[1][jj][kk], 0, 0, 0);                      \
        }                                                                     \
      }                                                                       \
    }                                                                         \
    if (((T) & 31) == 31) EPILOGUE(T)                                         \
  }

__global__ __launch_bounds__(256, 1) void k_main(const float* __restrict__ mf,
                                                 const float* __restrict__ HT,
                                                 const _Float16* __restrict__ HTh,
                                                 const _Float16* __restrict__ Ah,
                                                 const _Float16* __restrict__ mhT,
                                                 float* __restrict__ out) {
    __shared__ _Float16 tiles[3][2][128 * 64];  // 96KB, triple-buffered
    __shared__ _Float16 hbuf[2][N];             // 8KB
    __shared__ float red[2][4][64];             // 2KB

    int t = threadIdx.x;
    int jbase = (blockIdx.x >> 5) << 7;
    int f0 = (blockIdx.x & 31) << 1;
    int w = t >> 6, lane = t & 63, q = lane >> 4, l16 = lane & 15;
    int wj = (w & 1) << 6, wk = (w >> 1) << 6;

    // --- stage H rows (once) ---
#pragma unroll
    for (int s = 0; s < 2; ++s) {
        int idx = t + 256 * s;                // 0..511 ; fi=idx>>8, chunk=idx&255
        ((f16x8*)hbuf)[idx] = *(const f16x8*)&HTh[(size_t)(f0 + (idx >> 8)) * N + (idx & 255) * 8];
    }
    ((float*)red)[t] = 0.f;
    ((float*)red)[t + 256] = 0.f;

    // --- staging voffsets (global_load_lds: lane l -> ldsbase + l*16) ---
    int lrow = lane >> 3;                      // row within 8-row call
    int lchunk = (lane & 7) ^ lrow;            // logical chunk (XOR swizzle)
    int a_base = (jbase + w * 32 + lrow) * N + lchunk * 8;
    int b_base = (w * 32 + lrow) * N + lchunk * 8;   // + ktile*128*N per ktile
    int lds_w = w * 2048;                      // (w*32 rows)*64 halves

    // --- prologue: stage iters 0,1; read frags(0) ---
    STAGE_STEP(0)
    STAGE_STEP(1)
    WAITV8          // stage(0) complete (16 outstanding -> 8)
    LGKM0           // hbuf/red writes drained
    BAR

    f16x8 arA[2][4], brA[2][4], hA[2][2];
    f16x8 arB[2][4], brB[2][4], hB[2][2];
    READ_STEP(arA, brA, hA, 0, 0)

    f32x4 acc[2][4][4];
#pragma unroll
    for (int a = 0; a < 4; ++a)
#pragma unroll
        for (int b = 0; b < 4; ++b) {
            acc[0][a][b] = (f32x4){0.f, 0.f, 0.f, 0.f};
            acc[1][a][b] = (f32x4){0.f, 0.f, 0.f, 0.f};
        }

    // --- main loop: 2 iters per trip (ping-pong reg sets, static indexing) ---
    for (int tp = 0; tp < (NIT - 2) / 2; ++tp) {
        int t0 = tp * 2, t1 = t0 + 1;
        // half 0: cur = A, prefetch -> B
        STAGE_STEP(t0 + 2)
        WAITV8                                    // stage(t0+1) complete
        BAR
        READ_STEP(arB, brB, hB, (t0 + 1) % 3, ((t0 + 1) & 31) << 6)
        COMPUTE_STEP(arA, brA, hA, t0)
        LGKM0                                     // frag reads drained (WAR guard)
        BAR
        // half 1: cur = B, prefetch -> A
        STAGE_STEP(t1 + 2)
        WAITV8                                    // stage(t1+1) complete
        BAR
        READ_STEP(arA, brA, hA, (t1 + 1) % 3, ((t1 + 1) & 31) << 6)
        COMPUTE_STEP(arB, brB, hB, t1)
        LGKM0
        BAR
    }

    // --- peeled tail: t = NIT-2 (cur=A), t = NIT-1 (cur=B) ---
    WAITV0          // stage(NIT-1) complete (no stage(NIT) was issued)
    BAR
    READ_STEP(arB, brB, hB, (NIT - 1) % 3, ((NIT - 1) & 31) << 6)
    COMPUTE_STEP(arA, brA, hA, NIT - 2)
    LGKM0
    BAR
    COMPUTE_STEP(arB, brB, hB, NIT - 1)           // epilogue folds last ktile
    LGKM0
    BAR

    // --- cross-wave reduce + store ---
    if (t < 128) {
        int j = t;
#pragma unroll
        for (int fi = 0; fi < 2; ++fi) {
            float v = (j < 64) ? (red[fi][0][j] + red[fi][2][j])
                               : (red[fi][1][j - 64] + red[fi][3][j - 64]);
            out[(size_t)(jbase + j) * FOUT + f0 + fi] = v;
        }
    }
}

// ---------------- launch ----------------
extern "C" void kernel_launch(void* const* d_in, const int* in_sizes, int n_in,
                              void* d_out, int out_size, void* d_ws, size_t ws_size,
                              hipStream_t stream) {
    const float* X    = (const float*)d_in[0];
    const float* A    = (const float*)d_in[1];
    const float* mf   = (const float*)d_in[2];
    const float* mh   = (const float*)d_in[3];
    const float* W    = (const float*)d_in[4];
    const float* bias = (const float*)d_in[5];
    float* out = (float*)d_out;

    float*    HT  = (float*)d_ws;
    _Float16* HTh = (_Float16*)((char*)d_ws + 524288);
    _Float16* Ah  = (_Float16*)((char*)d_ws + 1048576);
    _Float16* mhT = (_Float16*)((char*)d_ws + 1048576 + 8388608);

    k_h<<<N / 4, 256, 0, stream>>>(X, W, bias, HT, HTh);
    k_a2h<<<(N * N / 4) / 256, 256, 0, stream>>>(A, Ah);
    k_mht<<<(N / 64) * (N / 64), 256, 0, stream>>>(mh, mhT);
    k_main<<<16 * 32, 256, 0, stream>>>(mf, HT, HTh, Ah, mhT, out);
}

// Round 3
// 1252.959 us; speedup vs baseline: 1.8143x; 1.1572x over previous
//
#include <hip/hip_runtime.h>
#include <hip/hip_bf16.h>

// Problem: N=2048, F_IN=128, F_OUT=64
// out[j,f] = sum_{i,k} A[j,i] H[i,f] mh[i,k] H[k,f] mf[j,k],  H = X@W + b
// R5: R2's verified 2-block/CU double-buffer structure, with:
//  - 32x32x16 f16 MFMA (2495 vs 2075 TF shape rate: -17% on the dominant pipe)
//  - fully hoisted LDS read addresses (8 base VGPRs + imm offsets; buf via
//    unroll-by-2) and SALU-advanced staging pointers -> VALU diet
//  - s_setprio(1) around the MFMA cluster (independent blocks per CU -> T5
//    attn-like regime)
// R3/R4 lessons: keep acc at 128 regs, keep 2 blocks/CU, no sched_barrier pins.

typedef __attribute__((ext_vector_type(8))) _Float16 f16x8;
typedef __attribute__((ext_vector_type(4))) _Float16 f16x4;
typedef __attribute__((ext_vector_type(16))) float f32x16;

#define N 2048
#define FOUT 64
#define FIN 128
#define NIT 512        // 16 ktiles * 32 i-steps

#define ZERO16 ((f32x16){0.f,0.f,0.f,0.f,0.f,0.f,0.f,0.f,0.f,0.f,0.f,0.f,0.f,0.f,0.f,0.f})
#define MFMA32(A,B,C) __builtin_amdgcn_mfma_f32_32x32x16_f16((A),(B),(C),0,0,0)

__device__ __forceinline__ void gl_lds16(const _Float16* g, _Float16* l) {
    __builtin_amdgcn_global_load_lds(
        (const __attribute__((address_space(1))) void*)g,
        (__attribute__((address_space(3))) void*)l, 16, 0, 0);
}

// ---------------- prep kernels ----------------

__global__ __launch_bounds__(256) void k_h(const float* __restrict__ X,
                                           const float* __restrict__ W,
                                           const float* __restrict__ bias,
                                           float* __restrict__ HT,
                                           _Float16* __restrict__ HTh) {
    __shared__ float Ws[FIN * FOUT];
    __shared__ float Xs[4 * FIN];
    int t = threadIdx.x;
#pragma unroll
    for (int s = 0; s < 32; ++s) Ws[t + 256 * s] = W[t + 256 * s];
    int i0 = blockIdx.x * 4;
#pragma unroll
    for (int s = 0; s < 2; ++s) { int idx = t + 256 * s; Xs[idx] = X[(size_t)i0 * FIN + idx]; }
    __syncthreads();
    int f = t & 63, il = t >> 6;
    float h = bias[f];
#pragma unroll
    for (int p = 0; p < FIN; ++p) h = fmaf(Xs[il * FIN + p], Ws[p * FOUT + f], h);
    int i = i0 + il;
    HT[f * N + i] = h;
    HTh[f * N + i] = (_Float16)h;
}

__global__ __launch_bounds__(256) void k_a2h(const float* __restrict__ A,
                                             _Float16* __restrict__ Ah) {
    int g = blockIdx.x * 256 + threadIdx.x;
    float4 v = ((const float4*)A)[g];
    f16x4 o;
    o[0] = (_Float16)v.x; o[1] = (_Float16)v.y; o[2] = (_Float16)v.z; o[3] = (_Float16)v.w;
    ((f16x4*)Ah)[g] = o;
}

__global__ __launch_bounds__(256) void k_mht(const float* __restrict__ mh,
                                             _Float16* __restrict__ mhT) {
    __shared__ float tile[64][65];
    int t = threadIdx.x;
    int bx = blockIdx.x & 31;
    int by = blockIdx.x >> 5;
#pragma unroll
    for (int s = 0; s < 16; ++s) {
        int lin = t + 256 * s;
        int r = lin >> 6, c = lin & 63;
        tile[r][c] = mh[(size_t)(by * 64 + r) * N + bx * 64 + c];
    }
    __syncthreads();
#pragma unroll
    for (int s = 0; s < 16; ++s) {
        int lin = t + 256 * s;
        int kr = lin >> 6, ic = lin & 63;
        mhT[(size_t)(bx * 64 + kr) * N + by * 64 + ic] = (_Float16)tile[ic][kr];
    }
}

// ---------------- main kernel ----------------
// grid 512 = 16 jtiles (bid>>5) * 32 fgroups (bid&31); block = 128j x 128k x 2f.
// Wave w: wj=(w&1)*64, wk=(w>>1)*64; per-wave 64x64 per f as 2x2 of 32x32.
// LDS tile row = 64 halves = 8 chunks of 16B; phys_chunk = log_chunk ^ (row&7).
// 32x32x16 frag slots: row/col = lane&31; slot (hi=lane>>5, e) holds
// i = chunk*8+e with chunk = ks*2+hi  (slot-consistent across A, B, h).
// C/D: col = lane&31, row = (r&3) + 8*(r>>2) + 4*hi   [m74/m101 verified].

#define STAGE(DBUF, IT)                                                        \
  {                                                                            \
    int ib_ = ((IT) & 31) << 6;                                                \
    int kt_ = (IT) >> 5;                                                       \
    const char* gA_ = (const char*)Ah + ((size_t)jbase * N + ib_) * 2;         \
    const char* gB_ = (const char*)mhT + ((size_t)kt_ * 128 * N + ib_) * 2;    \
    _Float16* la_ = &tiles[DBUF][0][lds_w];                                    \
    _Float16* lb_ = &tiles[DBUF][1][lds_w];                                    \
    _Pragma("unroll")                                                          \
    for (int c_ = 0; c_ < 4; ++c_) {                                           \
      gl_lds16((const _Float16*)(gA_ + (size_t)c_ * (16 * N) + vbyte), la_ + c_ * 512); \
      gl_lds16((const _Float16*)(gB_ + (size_t)c_ * (16 * N) + vbyte), lb_ + c_ * 512); \
    }                                                                          \
  }

#define COMPUTE_HALF(BUF, IT)                                                  \
  {                                                                            \
    const char* hb_ = (const char*)hbuf + ((((IT) & 31) << 6) * 2);            \
    __builtin_amdgcn_s_setprio(1);                                             \
    _Pragma("unroll")                                                          \
    for (int ks = 0; ks < 4; ++ks) {                                           \
      f16x8 a0 = *(const f16x8*)(tbase + addrA[ks] + (BUF) * 32768);           \
      f16x8 a1 = *(const f16x8*)(tbase + addrA[ks] + (BUF) * 32768 + 4096);    \
      f16x8 b0 = *(const f16x8*)(tbase + addrB[ks] + (BUF) * 32768 + 16384);   \
      f16x8 b1 = *(const f16x8*)(tbase + addrB[ks] + (BUF) * 32768 + 20480);   \
      f16x8 h0 = *(const f16x8*)(hb_ + hlb + ks * 32);                         \
      f16x8 h1 = *(const f16x8*)(hb_ + hlb + 4096 + ks * 32);                  \
      f16x8 a00 = a0 * h0, a10 = a1 * h0, a01 = a0 * h1, a11 = a1 * h1;        \
      acc[0][0][0] = MFMA32(a00, b0, acc[0][0][0]);                            \
      acc[0][0][1] = MFMA32(a00, b1, acc[0][0][1]);                            \
      acc[0][1][0] = MFMA32(a10, b0, acc[0][1][0]);                            \
      acc[0][1][1] = MFMA32(a10, b1, acc[0][1][1]);                            \
      acc[1][0][0] = MFMA32(a01, b0, acc[1][0][0]);                            \
      acc[1][0][1] = MFMA32(a01, b1, acc[1][0][1]);                            \
      acc[1][1][0] = MFMA32(a11, b0, acc[1][1][0]);                            \
      acc[1][1][1] = MFMA32(a11, b1, acc[1][1][1]);                            \
    }                                                                          \
    __builtin_amdgcn_s_setprio(0);                                             \
  }

#define EPILOGUE(IT)                                                           \
  {                                                                            \
    int kb_ = (((IT) >> 5) << 7) + wk;                                         \
    float hk0[2], hk1[2];                                                      \
    _Pragma("unroll")                                                          \
    for (int tk = 0; tk < 2; ++tk) {                                           \
      int kg = kb_ + tk * 32 + l31;                                            \
      hk0[tk] = HT[f0 * N + kg];                                               \
      hk1[tk] = HT[(f0 + 1) * N + kg];                                         \
    }                                                                          \
    _Pragma("unroll")                                                          \
    for (int tj = 0; tj < 2; ++tj) {                                           \
      int jr0 = jbase + wj + tj * 32 + hi * 4;                                 \
      _Pragma("unroll")                                                        \
      for (int r = 0; r < 16; ++r) {                                           \
        int jr = jr0 + (r & 3) + 8 * (r >> 2);                                 \
        float s0 = 0.f, s1 = 0.f;                                              \
        _Pragma("unroll")                                                      \
        for (int tk = 0; tk < 2; ++tk) {                                       \
          int kg = kb_ + tk * 32 + l31;                                        \
          float m = mf[(size_t)jr * N + kg];                                   \
          s0 = fmaf(acc[0][tj][tk][r], m * hk0[tk], s0);                       \
          s1 = fmaf(acc[1][tj][tk][r], m * hk1[tk], s1);                       \
        }                                                                      \
        s0 += __shfl_xor(s0, 1);  s1 += __shfl_xor(s1, 1);                     \
        s0 += __shfl_xor(s0, 2);  s1 += __shfl_xor(s1, 2);                     \
        s0 += __shfl_xor(s0, 4);  s1 += __shfl_xor(s1, 4);                     \
        s0 += __shfl_xor(s0, 8);  s1 += __shfl_xor(s1, 8);                     \
        s0 += __shfl_xor(s0, 16); s1 += __shfl_xor(s1, 16);                    \
        if (l31 == 0) {                                                        \
          int slot = tj * 32 + (r & 3) + 8 * (r >> 2) + 4 * hi;                \
          red[0][w][slot] += s0;                                               \
          red[1][w][slot] += s1;                                               \
        }                                                                      \
      }                                                                        \
    }                                                                          \
    _Pragma("unroll")                                                          \
    for (int f_ = 0; f_ < 2; ++f_)                                             \
      _Pragma("unroll")                                                        \
      for (int a_ = 0; a_ < 2; ++a_)                                           \
        _Pragma("unroll")                                                      \
        for (int b_ = 0; b_ < 2; ++b_) acc[f_][a_][b_] = ZERO16;               \
  }

__global__ __launch_bounds__(256, 2) void k_main(const float* __restrict__ mf,
                                                 const float* __restrict__ HT,
                                                 const _Float16* __restrict__ HTh,
                                                 const _Float16* __restrict__ Ah,
                                                 const _Float16* __restrict__ mhT,
                                                 float* __restrict__ out) {
    __shared__ _Float16 tiles[2][2][128 * 64];  // [buf][a=0/b=1][row*64+..] 64KB
    __shared__ _Float16 hbuf[2][N];             // H fp16 rows for f0,f1: 8KB
    __shared__ float red[2][4][64];             // 2KB

    int t = threadIdx.x;
    int jbase = (blockIdx.x >> 5) << 7;
    int f0 = (blockIdx.x & 31) << 1;
    int w = t >> 6, lane = t & 63;
    int l31 = lane & 31, hi = lane >> 5, l7 = lane & 7;
    int wj = (w & 1) << 6, wk = (w >> 1) << 6;

    // --- stage H rows (once) ---
#pragma unroll
    for (int s = 0; s < 2; ++s) {
        int idx = t + 256 * s;                // 0..511 ; fi=idx>>8, chunk=idx&255
        ((f16x8*)hbuf)[idx] = *(const f16x8*)&HTh[(size_t)(f0 + (idx >> 8)) * N + (idx & 255) * 8];
    }
    ((float*)red)[t] = 0.f;
    ((float*)red)[t + 256] = 0.f;

    // --- staging lane offset (global_load_lds: lane l -> ldsbase + l*16) ---
    int lrow = lane >> 3;                      // row within 8-row call
    int lchunk = (lane & 7) ^ lrow;            // logical chunk (XOR swizzle)
    int vbyte = ((w * 32 + lrow) * N + lchunk * 8) * 2;  // same for A and B
    int lds_w = w * 2048;                      // (w*32 rows)*64 halves

    // --- hoisted fragment read addresses (loop-invariant VGPRs) ---
    const char* tbase = (const char*)&tiles[0][0][0];
    int hlb = hi * 16;                         // h lane base (bytes)
    int addrA[4], addrB[4];
#pragma unroll
    for (int ks = 0; ks < 4; ++ks) {
        int chs = ((ks * 2 + hi) ^ l7) * 16;   // swizzled chunk byte offset
        addrA[ks] = (wj + l31) * 128 + chs;
        addrB[ks] = (wk + l31) * 128 + chs;
    }

    // --- prefetch iteration 0 ---
    STAGE(0, 0)

    f32x16 acc[2][2][2];
#pragma unroll
    for (int f_ = 0; f_ < 2; ++f_)
#pragma unroll
        for (int a_ = 0; a_ < 2; ++a_)
#pragma unroll
            for (int b_ = 0; b_ < 2; ++b_) acc[f_][a_][b_] = ZERO16;

    for (int tp = 0; tp < NIT / 2; ++tp) {
        int it0 = tp * 2;
        // ---- half A: compute buf0, prefetch -> buf1 ----
        __syncthreads();                       // drains stage(it0) (8 loads)
        STAGE(1, it0 + 1)
        COMPUTE_HALF(0, it0)
        // it0 even -> never an epilogue boundary
        // ---- half B: compute buf1, prefetch -> buf0 ----
        __syncthreads();                       // drains stage(it0+1)
        if (tp != NIT / 2 - 1) STAGE(0, it0 + 2)
        COMPUTE_HALF(1, it0 + 1)
        if (((it0 + 1) & 31) == 31) EPILOGUE(it0 + 1)
    }

    // --- cross-wave reduce + store ---
    __syncthreads();
    if (t < 128) {
        int j = t;
#pragma unroll
        for (int fi = 0; fi < 2; ++fi) {
            float v = (j < 64) ? (red[fi][0][j] + red[fi][2][j])
                               : (red[fi][1][j - 64] + red[fi][3][j - 64]);
            out[(size_t)(jbase + j) * FOUT + f0 + fi] = v;
        }
    }
}

// ---------------- launch ----------------
extern "C" void kernel_launch(void* const* d_in, const int* in_sizes, int n_in,
                              void* d_out, int out_size, void* d_ws, size_t ws_size,
                              hipStream_t stream) {
    const float* X    = (const float*)d_in[0];
    const float* A    = (const float*)d_in[1];
    const float* mf   = (const float*)d_in[2];
    const float* mh   = (const float*)d_in[3];
    const float* W    = (const float*)d_in[4];
    const float* bias = (const float*)d_in[5];
    float* out = (float*)d_out;

    float*    HT  = (float*)d_ws;
    _Float16* HTh = (_Float16*)((char*)d_ws + 524288);
    _Float16* Ah  = (_Float16*)((char*)d_ws + 1048576);
    _Float16* mhT = (_Float16*)((char*)d_ws + 1048576 + 8388608);

    k_h<<<N / 4, 256, 0, stream>>>(X, W, bias, HT, HTh);
    k_a2h<<<(N * N / 4) / 256, 256, 0, stream>>>(A, Ah);
    k_mht<<<(N / 64) * (N / 64), 256, 0, stream>>>(mh, mhT);
    k_main<<<16 * 32, 256, 0, stream>>>(mf, HT, HTh, Ah, mhT, out);
}

// Round 4
// 1049.032 us; speedup vs baseline: 2.1670x; 1.1944x over previous
//
#include <hip/hip_runtime.h>
#include <hip/hip_bf16.h>

// Problem: N=2048, F_IN=128, F_OUT=64
// out[j,f] = sum_{i,k} A[j,i] H[i,f] mh[i,k] H[k,f] mf[j,k],  H = X@W + b
// R6: occupancy attack. R5 analysis showed ~60% of wall is latency/stall at
// 2 waves/SIMD (LDS-limited occupancy), with MFMA/VALU/LDS pipes each <25%
// absolute. So: BI 64->32 (LDS 75.8 -> 43KB) + k-split x2 (grid 1024,
// out = sum of 2 halves via atomicAdd on zeroed out; linear in k-sum) ->
// target 3 blocks/CU. MFMA back to 16x16x32 with R2's measured-0-conflict
// read patterns; 4-chunk swizzle re-derived: phys = log ^ ((row>>1)&3).
// Keeps R5's hoisted addresses + setprio. R3 lesson: acc stays 128 regs.

typedef __attribute__((ext_vector_type(8))) _Float16 f16x8;
typedef __attribute__((ext_vector_type(4))) _Float16 f16x4;
typedef __attribute__((ext_vector_type(4))) float f32x4;

#define N 2048
#define FOUT 64
#define FIN 128
#define NIT 512        // 8 ktiles (per k-half) * 64 i-steps

#define MFMA16(A,B,C) __builtin_amdgcn_mfma_f32_16x16x32_f16((A),(B),(C),0,0,0)

__device__ __forceinline__ void gl_lds16(const _Float16* g, _Float16* l) {
    __builtin_amdgcn_global_load_lds(
        (const __attribute__((address_space(1))) void*)g,
        (__attribute__((address_space(3))) void*)l, 16, 0, 0);
}

// ---------------- prep kernels ----------------

__global__ __launch_bounds__(256) void k_zero(float* __restrict__ out) {
    ((float4*)out)[blockIdx.x * 256 + threadIdx.x] = make_float4(0.f, 0.f, 0.f, 0.f);
}

__global__ __launch_bounds__(256) void k_h(const float* __restrict__ X,
                                           const float* __restrict__ W,
                                           const float* __restrict__ bias,
                                           float* __restrict__ HT,
                                           _Float16* __restrict__ HTh) {
    __shared__ float Ws[FIN * FOUT];
    __shared__ float Xs[4 * FIN];
    int t = threadIdx.x;
#pragma unroll
    for (int s = 0; s < 32; ++s) Ws[t + 256 * s] = W[t + 256 * s];
    int i0 = blockIdx.x * 4;
#pragma unroll
    for (int s = 0; s < 2; ++s) { int idx = t + 256 * s; Xs[idx] = X[(size_t)i0 * FIN + idx]; }
    __syncthreads();
    int f = t & 63, il = t >> 6;
    float h = bias[f];
#pragma unroll
    for (int p = 0; p < FIN; ++p) h = fmaf(Xs[il * FIN + p], Ws[p * FOUT + f], h);
    int i = i0 + il;
    HT[f * N + i] = h;
    HTh[f * N + i] = (_Float16)h;
}

__global__ __launch_bounds__(256) void k_a2h(const float* __restrict__ A,
                                             _Float16* __restrict__ Ah) {
    int g = blockIdx.x * 256 + threadIdx.x;
    float4 v = ((const float4*)A)[g];
    f16x4 o;
    o[0] = (_Float16)v.x; o[1] = (_Float16)v.y; o[2] = (_Float16)v.z; o[3] = (_Float16)v.w;
    ((f16x4*)Ah)[g] = o;
}

__global__ __launch_bounds__(256) void k_mht(const float* __restrict__ mh,
                                             _Float16* __restrict__ mhT) {
    __shared__ float tile[64][65];
    int t = threadIdx.x;
    int bx = blockIdx.x & 31;
    int by = blockIdx.x >> 5;
#pragma unroll
    for (int s = 0; s < 16; ++s) {
        int lin = t + 256 * s;
        int r = lin >> 6, c = lin & 63;
        tile[r][c] = mh[(size_t)(by * 64 + r) * N + bx * 64 + c];
    }
    __syncthreads();
#pragma unroll
    for (int s = 0; s < 16; ++s) {
        int lin = t + 256 * s;
        int kr = lin >> 6, ic = lin & 63;
        mhT[(size_t)(bx * 64 + kr) * N + by * 64 + ic] = (_Float16)tile[ic][kr];
    }
}

// ---------------- main kernel ----------------
// grid 1024 = 16 jtiles (bid>>6) * 32 fgroups ((bid>>1)&31) * 2 khalves (bid&1).
// block = 128j x 128k x 2f per k-half; wave w: wj=(w&1)*64, wk=(w>>1)*64.
// LDS tile row = 32 halves = 4 chunks of 16B; phys_chunk = log ^ ((row>>1)&3)
// (derived so each consecutive-8-lane group of a b128 frag read hits 8
// distinct 16B slots: slot = (row&1)*4 + phys -> conflict-free).

#define STAGE(DBUF, IT)                                                        \
  {                                                                            \
    int ib_ = ((IT) & 63) << 5;                                                \
    int kt_ = (IT) >> 6;                                                       \
    const _Float16* pa_ = Ah + a_base + ib_;                                   \
    const _Float16* pb_ = mhT + b_base + (size_t)kt_ * 128 * N + ib_;          \
    _Float16* la_ = &tiles[DBUF][0][w * 1024];                                 \
    _Float16* lb_ = &tiles[DBUF][1][w * 1024];                                 \
    _Pragma("unroll")                                                          \
    for (int c_ = 0; c_ < 2; ++c_) {                                           \
      gl_lds16(pa_ + c_ * 16 * N, la_ + c_ * 512);                             \
      gl_lds16(pb_ + c_ * 16 * N, lb_ + c_ * 512);                             \
    }                                                                          \
  }

#define COMPUTE_HALF(BUF, IT)                                                  \
  {                                                                            \
    const char* hb_ = (const char*)hbuf + (((IT) & 63) << 6);                  \
    f16x8 ar[4], br[4];                                                        \
    _Pragma("unroll")                                                          \
    for (int x_ = 0; x_ < 4; ++x_)                                             \
      ar[x_] = *(const f16x8*)(tbase + (BUF) * 16384 + faA + x_ * 1024);       \
    _Pragma("unroll")                                                          \
    for (int x_ = 0; x_ < 4; ++x_)                                             \
      br[x_] = *(const f16x8*)(tbase + (BUF) * 16384 + 8192 + faB + x_ * 1024);\
    f16x8 h0 = *(const f16x8*)(hb_ + hq);                                      \
    f16x8 h1 = *(const f16x8*)(hb_ + 4096 + hq);                               \
    __builtin_amdgcn_s_setprio(1);                                             \
    _Pragma("unroll")                                                          \
    for (int jj = 0; jj < 4; ++jj) {                                           \
      f16x8 a0 = ar[jj] * h0;                                                  \
      f16x8 a1 = ar[jj] * h1;                                                  \
      _Pragma("unroll")                                                        \
      for (int kk = 0; kk < 4; ++kk) {                                         \
        acc[0][jj][kk] = MFMA16(a0, br[kk], acc[0][jj][kk]);                   \
        acc[1][jj][kk] = MFMA16(a1, br[kk], acc[1][jj][kk]);                   \
      }                                                                        \
    }                                                                          \
    __builtin_amdgcn_s_setprio(0);                                             \
    if (((IT) & 63) == 63) EPILOGUE(IT)                                        \
  }

#define EPILOGUE(IT)                                                           \
  {                                                                            \
    int kb_ = khalf + (((IT) >> 6) << 7);                                      \
    _Pragma("unroll")                                                          \
    for (int jj = 0; jj < 4; ++jj) {                                           \
      float t0[4] = {0.f, 0.f, 0.f, 0.f};                                      \
      float t1[4] = {0.f, 0.f, 0.f, 0.f};                                      \
      int jrow = jbase + wj + jj * 16 + q * 4;                                 \
      _Pragma("unroll")                                                        \
      for (int kk = 0; kk < 4; ++kk) {                                         \
        int kg = kb_ + wk + kk * 16 + l16;                                     \
        float hk0 = HT[f0 * N + kg];                                           \
        float hk1 = HT[(f0 + 1) * N + kg];                                     \
        _Pragma("unroll")                                                      \
        for (int r = 0; r < 4; ++r) {                                          \
          float m = mf[(size_t)(jrow + r) * N + kg];                           \
          t0[r] = fmaf(acc[0][jj][kk][r], m * hk0, t0[r]);                     \
          t1[r] = fmaf(acc[1][jj][kk][r], m * hk1, t1[r]);                     \
        }                                                                      \
      }                                                                        \
      _Pragma("unroll")                                                        \
      for (int r = 0; r < 4; ++r) {                                            \
        float v0 = t0[r], v1 = t1[r];                                          \
        v0 += __shfl_xor(v0, 1); v1 += __shfl_xor(v1, 1);                      \
        v0 += __shfl_xor(v0, 2); v1 += __shfl_xor(v1, 2);                      \
        v0 += __shfl_xor(v0, 4); v1 += __shfl_xor(v1, 4);                      \
        v0 += __shfl_xor(v0, 8); v1 += __shfl_xor(v1, 8);                      \
        if (l16 == 0) {                                                        \
          red[0][w][jj * 16 + q * 4 + r] += v0;                                \
          red[1][w][jj * 16 + q * 4 + r] += v1;                                \
        }                                                                      \
      }                                                                        \
    }                                                                          \
    _Pragma("unroll")                                                          \
    for (int a_ = 0; a_ < 4; ++a_)                                             \
      _Pragma("unroll")                                                        \
      for (int b_ = 0; b_ < 4; ++b_) {                                         \
        acc[0][a_][b_] = (f32x4){0.f, 0.f, 0.f, 0.f};                          \
        acc[1][a_][b_] = (f32x4){0.f, 0.f, 0.f, 0.f};                          \
      }                                                                        \
  }

__global__ __launch_bounds__(256, 2) void k_main(const float* __restrict__ mf,
                                                 const float* __restrict__ HT,
                                                 const _Float16* __restrict__ HTh,
                                                 const _Float16* __restrict__ Ah,
                                                 const _Float16* __restrict__ mhT,
                                                 float* __restrict__ out) {
    __shared__ _Float16 tiles[2][2][128 * 32];  // [buf][a=0/b=1] 32KB
    __shared__ _Float16 hbuf[2][N];             // H fp16 rows for f0,f1: 8KB
    __shared__ float red[2][4][64];             // 2KB

    int t = threadIdx.x;
    int jbase = (blockIdx.x >> 6) << 7;
    int f0 = ((blockIdx.x >> 1) & 31) << 1;
    int khalf = (blockIdx.x & 1) << 10;         // 0 or 1024
    int w = t >> 6, lane = t & 63, q = lane >> 4, l16 = lane & 15;
    int wj = (w & 1) << 6, wk = (w >> 1) << 6;

    // --- stage H rows (once) ---
#pragma unroll
    for (int s = 0; s < 2; ++s) {
        int idx = t + 256 * s;                // 0..511 ; fi=idx>>8, chunk=idx&255
        ((f16x8*)hbuf)[idx] = *(const f16x8*)&HTh[(size_t)(f0 + (idx >> 8)) * N + (idx & 255) * 8];
    }
    ((float*)red)[t] = 0.f;
    ((float*)red)[t + 256] = 0.f;

    // --- staging source offsets (global_load_lds: lane l -> ldsbase + l*16) ---
    // per call: 16 rows x 32 halves; lane -> (row = lane>>2, phys = lane&3);
    // source logical chunk = (lane&3) ^ ((row>>1)&3) = (lane&3) ^ ((lane>>3)&3)
    int chlog = (lane & 3) ^ ((lane >> 3) & 3);
    size_t a_base = (size_t)(jbase + w * 32 + (lane >> 2)) * N + chlog * 8;
    size_t b_base = (size_t)(khalf + w * 32 + (lane >> 2)) * N + chlog * 8;

    // --- hoisted fragment read addresses (bytes) ---
    const char* tbase = (const char*)&tiles[0][0][0];
    int chr = (q ^ ((l16 >> 1) & 3)) * 16;     // phys chunk byte offset
    int faA = (wj + l16) * 64 + chr;           // row stride 64B
    int faB = (wk + l16) * 64 + chr;
    int hq = q * 16;

    // --- prefetch iteration 0 ---
    STAGE(0, 0)

    f32x4 acc[2][4][4];
#pragma unroll
    for (int a = 0; a < 4; ++a)
#pragma unroll
        for (int b = 0; b < 4; ++b) {
            acc[0][a][b] = (f32x4){0.f, 0.f, 0.f, 0.f};
            acc[1][a][b] = (f32x4){0.f, 0.f, 0.f, 0.f};
        }

    for (int tp = 0; tp < NIT / 2; ++tp) {
        int it0 = tp * 2;
        // ---- half A: compute buf0, prefetch -> buf1 ----
        __syncthreads();                       // drains stage(it0) (8 loads/wave)
        STAGE(1, it0 + 1)
        COMPUTE_HALF(0, it0)
        // it0 even -> never an epilogue boundary (epilogues at it&63==63, odd)
        // ---- half B: compute buf1, prefetch -> buf0 ----
        __syncthreads();                       // drains stage(it0+1)
        if (tp != NIT / 2 - 1) STAGE(0, it0 + 2)
        COMPUTE_HALF(1, it0 + 1)
    }

    // --- cross-wave reduce + atomic add into out (2 k-halves sum here) ---
    __syncthreads();
    if (t < 128) {
        int j = t;
#pragma unroll
        for (int fi = 0; fi < 2; ++fi) {
            float v = (j < 64) ? (red[fi][0][j] + red[fi][2][j])
                               : (red[fi][1][j - 64] + red[fi][3][j - 64]);
            atomicAdd(&out[(size_t)(jbase + j) * FOUT + f0 + fi], v);
        }
    }
}

// ---------------- launch ----------------
extern "C" void kernel_launch(void* const* d_in, const int* in_sizes, int n_in,
                              void* d_out, int out_size, void* d_ws, size_t ws_size,
                              hipStream_t stream) {
    const float* X    = (const float*)d_in[0];
    const float* A    = (const float*)d_in[1];
    const float* mf   = (const float*)d_in[2];
    const float* mh   = (const float*)d_in[3];
    const float* W    = (const float*)d_in[4];
    const float* bias = (const float*)d_in[5];
    float* out = (float*)d_out;

    float*    HT  = (float*)d_ws;
    _Float16* HTh = (_Float16*)((char*)d_ws + 524288);
    _Float16* Ah  = (_Float16*)((char*)d_ws + 1048576);
    _Float16* mhT = (_Float16*)((char*)d_ws + 1048576 + 8388608);

    k_zero<<<(N * FOUT / 4) / 256, 256, 0, stream>>>(out);
    k_h<<<N / 4, 256, 0, stream>>>(X, W, bias, HT, HTh);
    k_a2h<<<(N * N / 4) / 256, 256, 0, stream>>>(A, Ah);
    k_mht<<<(N / 64) * (N / 64), 256, 0, stream>>>(mh, mhT);
    k_main<<<16 * 32 * 2, 256, 0, stream>>>(mf, HT, HTh, Ah, mhT, out);
}